// Round 7
// baseline (196.259 us; speedup 1.0000x reference)
//
#include <hip/hip_runtime.h>
#include <stdint.h>

typedef unsigned short u16;
typedef __attribute__((ext_vector_type(8))) short bf16x8;
typedef __attribute__((ext_vector_type(4))) float f32x4;

// ---------- helpers ----------
__device__ __forceinline__ u16 f2bf(float f) {
  union { float f; unsigned u; } v; v.f = f;
  unsigned r = v.u + 0x7fffu + ((v.u >> 16) & 1u);  // round-to-nearest-even
  return (u16)(r >> 16);
}

__device__ __forceinline__ void async_copy16(u16* lds_dst, const u16* g_src) {
  __builtin_amdgcn_global_load_lds(
      (const __attribute__((address_space(1))) unsigned*)(g_src),
      (__attribute__((address_space(3))) unsigned*)(lds_dst),
      16, 0, 0);
}

#define MFMA16(a, b, c) __builtin_amdgcn_mfma_f32_16x16x32_bf16((a), (b), (c), 0, 0, 0)
#define BARRIER() asm volatile("s_barrier" ::: "memory")
#define WAIT_LGKM0() do { asm volatile("s_waitcnt lgkmcnt(0)" ::: "memory"); __builtin_amdgcn_sched_barrier(0); } while (0)

// ---------- convert f32 -> bf16 (vectorized) ----------
__global__ void cvt_bf16_kernel(const float* __restrict__ in, u16* __restrict__ out, int n4) {
  int i = blockIdx.x * blockDim.x + threadIdx.x;
  int stride = gridDim.x * blockDim.x;
  for (; i < n4; i += stride) {
    float4 v = ((const float4*)in)[i];
    ushort4 o;
    o.x = f2bf(v.x); o.y = f2bf(v.y); o.z = f2bf(v.z); o.w = f2bf(v.w);
    ((ushort4*)out)[i] = o;
  }
}

// ---------- tiled transpose + convert: in [R][C] f32 -> out [C][R] bf16 ----------
__global__ void transpose_cvt_kernel(const float* __restrict__ in, u16* __restrict__ out,
                                     int R, int C) {
  __shared__ float tile[32][33];
  int bx = blockIdx.x * 32;
  int by = blockIdx.y * 32;
  int tx = threadIdx.x & 31, ty = threadIdx.x >> 5;
#pragma unroll
  for (int j = 0; j < 32; j += 8)
    tile[ty + j][tx] = in[(size_t)(by + ty + j) * C + bx + tx];
  __syncthreads();
#pragma unroll
  for (int j = 0; j < 32; j += 8)
    out[(size_t)(bx + ty + j) * R + by + tx] = f2bf(tile[tx][ty + j]);
}

// ---------- 256x256 8-phase GEMM (exact m201-template port), K=1024 ----------
// 512 thr = 8 waves (2M x 4N), wave tile 128x64, acc[8][4]. BK=64.
// LDS 128KB: [parity][half(128x64)] for A and B, XOR-swizzled (row&7)<<4 via
// pre-swizzled global source. Half-tile stage order per tile: B-lo, B-hi,
// A-lo, A-hi (read-before-overwrite verified per wave/phase). Counted
// vmcnt(6) ONLY at phases 4/8; lgkmcnt(8) after the 12-read phase; setprio
// around each 16-MFMA cluster; sched_barrier(0) fences per rule #18.
__global__ __launch_bounds__(512, 2)
void gemm8ph(const u16* __restrict__ A, const u16* __restrict__ BT,
             u16* __restrict__ q_o, u16* __restrict__ k_o, u16* __restrict__ vt_o) {
  constexpr int K = 1024;
  constexpr int NTI = 8;  // iterations, 2 K-tiles each
  __shared__ u16 As[2][2][8192];  // [parity][half][128*64]
  __shared__ u16 Bs[2][2][8192];

  const int t = threadIdx.x;
  const int w = t >> 6, l = t & 63;
  const int lr = l & 15, g = l >> 4;
  const int wm = w >> 2, wn = w & 3;
  const int m0 = blockIdx.x * 256, n0 = blockIdx.y * 256;

  // staging: per half-tile, thread t covers rows (t>>3), (t>>3)+64 at
  // byte-seg (t&7)*16; source col pre-swizzled, LDS dst linear.
  const int r = t >> 3;
  const int sw = ((t & 7) * 16) ^ ((r & 7) << 4);
  const u16* pA = A + (size_t)(m0 + r) * K + (sw >> 1);
  const u16* pB = BT + (size_t)(n0 + r) * K + (sw >> 1);

#define STGA(par, h, kk)                                                          \
  do {                                                                            \
    async_copy16(&As[par][h][t * 8],        pA + (size_t)((h) * 128) * K + (kk)); \
    async_copy16(&As[par][h][4096 + t * 8], pA + (size_t)((h) * 128 + 64) * K + (kk)); \
  } while (0)
#define STGB(par, h, kk)                                                          \
  do {                                                                            \
    async_copy16(&Bs[par][h][t * 8],        pB + (size_t)((h) * 128) * K + (kk)); \
    async_copy16(&Bs[par][h][4096 + t * 8], pB + (size_t)((h) * 128 + 64) * K + (kk)); \
  } while (0)

  f32x4 acc[8][4] = {};

  // prologue: tile0 full (4 half-tiles) + tile1 first 3 half-tiles = 14 loads
  STGB(0, 0, 0); STGB(0, 1, 0); STGA(0, 0, 0); STGA(0, 1, 0);
  STGB(1, 0, 64); STGB(1, 1, 64); STGA(1, 0, 64);
  asm volatile("s_waitcnt vmcnt(6)" ::: "memory");  // tile0 landed
  BARRIER();

  const int bh_ = wn >> 1;        // B half this wave reads
  const int br0 = (wn & 1) * 64;  // row base within that half

  bf16x8 a03[4][2], a47[4][2], bb[4][2];

#define RD_A(par, dst, rbase)                                                       \
  _Pragma("unroll") for (int mf = 0; mf < 4; ++mf)                                  \
  _Pragma("unroll") for (int ks = 0; ks < 2; ++ks) {                                \
    const int r2 = (rbase) + mf * 16 + lr;                                          \
    dst[mf][ks] = *(const bf16x8*)&As[par][wm][r2 * 64 + (((ks * 64 + g * 16) ^ ((r2 & 7) << 4)) >> 1)]; \
  }
#define RD_B(par, nf0, nf1)                                                         \
  _Pragma("unroll") for (int nf = (nf0); nf < (nf1); ++nf)                          \
  _Pragma("unroll") for (int ks = 0; ks < 2; ++ks) {                                \
    const int r2 = br0 + nf * 16 + lr;                                              \
    bb[nf][ks] = *(const bf16x8*)&Bs[par][bh_][r2 * 64 + (((ks * 64 + g * 16) ^ ((r2 & 7) << 4)) >> 1)]; \
  }
#define MFMA_Q(mbase, nf0, nf1, asrc)                                               \
  __builtin_amdgcn_s_setprio(1);                                                    \
  _Pragma("unroll") for (int mf = 0; mf < 4; ++mf)                                  \
  _Pragma("unroll") for (int nf = (nf0); nf < (nf1); ++nf) {                        \
    acc[(mbase) + mf][nf] = MFMA16(asrc[mf][0], bb[nf][0], acc[(mbase) + mf][nf]);  \
    acc[(mbase) + mf][nf] = MFMA16(asrc[mf][1], bb[nf][1], acc[(mbase) + mf][nf]);  \
  }                                                                                 \
  __builtin_amdgcn_s_setprio(0);                                                    \
  __builtin_amdgcn_sched_barrier(0)

  for (int it = 0; it < NTI; ++it) {
    const int k1 = (2 * it + 1) * 64, k2 = (2 * it + 2) * 64, k3 = (2 * it + 3) * 64;
    const bool st2 = (2 * it + 2) < (K / 64), st3 = (2 * it + 3) < (K / 64);

    // ===== tile T = 2it (parity 0) =====
    // P1: read a03+b01(T), stage A-hi(T+1)
    RD_A(0, a03, 0)
    RD_B(0, 0, 2)
    STGA(1, 1, k1);
    asm volatile("s_waitcnt lgkmcnt(8)" ::: "memory");
    BARRIER();
    WAIT_LGKM0();
    MFMA_Q(0, 0, 2, a03);
    BARRIER();

    // P2: read b23(T), stage B-lo(T+2)
    RD_B(0, 2, 4)
    if (st2) STGB(0, 0, k2);
    BARRIER();
    WAIT_LGKM0();
    MFMA_Q(0, 2, 4, a03);
    BARRIER();

    // P3: read a47(T), stage B-hi(T+2)
    RD_A(0, a47, 64)
    if (st2) STGB(0, 1, k2);
    BARRIER();
    WAIT_LGKM0();
    MFMA_Q(4, 0, 2, a47);
    BARRIER();

    // P4: stage A-lo(T+2), counted vmcnt -> tile T+1 landed
    if (st2) STGA(0, 0, k2);
    if (it < NTI - 1) asm volatile("s_waitcnt vmcnt(6)" ::: "memory");
    else              asm volatile("s_waitcnt vmcnt(0)" ::: "memory");
    BARRIER();
    MFMA_Q(4, 2, 4, a47);
    BARRIER();

    // ===== tile T+1 (parity 1) =====
    // P5: read a03+b01(T+1), stage A-hi(T+2)
    RD_A(1, a03, 0)
    RD_B(1, 0, 2)
    if (st2) STGA(0, 1, k2);
    asm volatile("s_waitcnt lgkmcnt(8)" ::: "memory");
    BARRIER();
    WAIT_LGKM0();
    MFMA_Q(0, 0, 2, a03);
    BARRIER();

    // P6: read b23(T+1), stage B-lo(T+3)
    RD_B(1, 2, 4)
    if (st3) STGB(1, 0, k3);
    BARRIER();
    WAIT_LGKM0();
    MFMA_Q(0, 2, 4, a03);
    BARRIER();

    // P7: read a47(T+1), stage B-hi(T+3)
    RD_A(1, a47, 64)
    if (st3) STGB(1, 1, k3);
    BARRIER();
    WAIT_LGKM0();
    MFMA_Q(4, 0, 2, a47);
    BARRIER();

    // P8: stage A-lo(T+3), counted vmcnt -> tile T+2 landed
    if (st3) STGA(1, 0, k3);
    if (it < NTI - 1) asm volatile("s_waitcnt vmcnt(6)" ::: "memory");
    BARRIER();
    MFMA_Q(4, 2, 4, a47);
    BARRIER();
  }
#undef RD_A
#undef RD_B
#undef MFMA_Q
#undef STGA
#undef STGB

  // ---- epilogue: qkv scatter (q*0.125, k, vT) ----
#pragma unroll
  for (int mf = 0; mf < 8; ++mf) {
#pragma unroll
    for (int nf = 0; nf < 4; ++nf) {
      const int col = n0 + wn * 64 + nf * 16 + lr;
#pragma unroll
      for (int j = 0; j < 4; ++j) {
        const int row = m0 + wm * 128 + mf * 16 + g * 4 + j;
        const float v = acc[mf][nf][j];
        const int which = col >> 10, rr = col & 1023;
        const int h = rr >> 6, hd = rr & 63;
        const int b = row >> 11, s = row & 2047;
        const size_t bh = (size_t)b * 16 + h;
        if (which == 0)      q_o[(bh * 2048 + s) * 64 + hd] = f2bf(v * 0.125f);
        else if (which == 1) k_o[(bh * 2048 + s) * 64 + hd] = f2bf(v);
        else                 vt_o[(bh * 64 + hd) * 2048 + s] = f2bf(v);
      }
    }
  }
}

// ---------- 2-phase 128x128 GEMM (proj): f32 out ----------
__global__ __launch_bounds__(256, 2)
void gemm2ph(const u16* __restrict__ A, const u16* __restrict__ BT,
             int K, int N, float* __restrict__ f_o) {
  __shared__ u16 As[2][128 * 64];
  __shared__ u16 Bs[2][128 * 64];

  const int t = threadIdx.x;
  const int w = t >> 6, l = t & 63;
  const int lr = l & 15, g = l >> 4;
  const int wm = (w >> 1) * 64, wn = (w & 1) * 64;
  const int m0 = blockIdx.x * 128, n0 = blockIdx.y * 128;

  const int r = t >> 3;
  const int sw = ((t & 7) * 16) ^ ((r & 7) << 4);
  const u16* pA = A + (size_t)(m0 + r) * K + (sw >> 1);
  const u16* pB = BT + (size_t)(n0 + r) * K + (sw >> 1);

#define STG(buf, kk)                                                    \
  do {                                                                  \
    async_copy16(&As[buf][t * 8],        pA + (kk));                    \
    async_copy16(&As[buf][2048 + t * 8], pA + (size_t)32 * K + (kk));   \
    async_copy16(&As[buf][4096 + t * 8], pA + (size_t)64 * K + (kk));   \
    async_copy16(&As[buf][6144 + t * 8], pA + (size_t)96 * K + (kk));   \
    async_copy16(&Bs[buf][t * 8],        pB + (kk));                    \
    async_copy16(&Bs[buf][2048 + t * 8], pB + (size_t)32 * K + (kk));   \
    async_copy16(&Bs[buf][4096 + t * 8], pB + (size_t)64 * K + (kk));   \
    async_copy16(&Bs[buf][6144 + t * 8], pB + (size_t)96 * K + (kk));   \
  } while (0)

  f32x4 acc[4][4] = {};

  STG(0, 0);
  __syncthreads();

  const int NTt = K / 64;
  for (int T = 0; T < NTt; ++T) {
    const int cur = T & 1;
    if (T + 1 < NTt) STG(cur ^ 1, (T + 1) * 64);

    bf16x8 af[4][2], bfr[4][2];
#pragma unroll
    for (int mf = 0; mf < 4; ++mf)
#pragma unroll
      for (int ks = 0; ks < 2; ++ks) {
        const int row = wm + mf * 16 + lr;
        af[mf][ks] = *(const bf16x8*)&As[cur][row * 64 + (((ks * 64 + g * 16) ^ ((row & 7) << 4)) >> 1)];
      }
#pragma unroll
    for (int nf = 0; nf < 4; ++nf)
#pragma unroll
      for (int ks = 0; ks < 2; ++ks) {
        const int row = wn + nf * 16 + lr;
        bfr[nf][ks] = *(const bf16x8*)&Bs[cur][row * 64 + (((ks * 64 + g * 16) ^ ((row & 7) << 4)) >> 1)];
      }
#pragma unroll
    for (int mf = 0; mf < 4; ++mf)
#pragma unroll
      for (int nf = 0; nf < 4; ++nf) {
        acc[mf][nf] = MFMA16(af[mf][0], bfr[nf][0], acc[mf][nf]);
        acc[mf][nf] = MFMA16(af[mf][1], bfr[nf][1], acc[mf][nf]);
      }
    __syncthreads();
  }
#undef STG

#pragma unroll
  for (int mf = 0; mf < 4; ++mf)
#pragma unroll
    for (int nf = 0; nf < 4; ++nf) {
      const int col = n0 + wn + nf * 16 + lr;
#pragma unroll
      for (int j = 0; j < 4; ++j) {
        const int row = m0 + wm + mf * 16 + g * 4 + j;
        f_o[(size_t)row * N + col] = acc[mf][nf][j];
      }
    }
}

// ---------- flash attention (v3, unchanged) ----------
__global__ __launch_bounds__(256, 2)
void attn_kernel(const u16* __restrict__ qws, const u16* __restrict__ kws,
                 const u16* __restrict__ vtws, u16* __restrict__ ybf) {
  __shared__ u16 Ksh[2][64 * 64];
  __shared__ u16 VTsh[2][64 * 64];
  __shared__ u16 Psh[4][32 * 64];

  const int bh = blockIdx.x & 63;
  const int qtile = 15 - (blockIdx.x >> 6);
  const int t = threadIdx.x;
  const int w = t >> 6, l = t & 63;
  const int lr = l & 15, g = l >> 4;
  const int q0 = qtile * 128 + w * 32;

  bf16x8 qf[2][2];
#pragma unroll
  for (int mf = 0; mf < 2; ++mf) {
    const u16* qb = qws + ((size_t)bh * 2048 + q0 + mf * 16 + lr) * 64 + g * 8;
#pragma unroll
    for (int ks = 0; ks < 2; ++ks) qf[mf][ks] = *(const bf16x8*)(qb + ks * 32);
  }

  f32x4 oacc[2][4] = {};
  float lrun[2][4] = {};

  const int srow = t >> 3;
  const int ssw = ((t & 7) * 16) ^ ((srow & 7) << 4);
  const u16* kb0 = kws + ((size_t)bh * 2048 + srow) * 64 + (ssw >> 1);
  const u16* vb0 = vtws + ((size_t)bh * 64 + srow) * 2048 + (ssw >> 1);

#define STAGE(kv0, buf)                                                \
  do {                                                                 \
    async_copy16(&Ksh[buf][t * 8],          kb0 + (size_t)(kv0)*64);   \
    async_copy16(&Ksh[buf][(t + 256) * 8],  kb0 + (size_t)((kv0)+32)*64); \
    async_copy16(&VTsh[buf][t * 8],         vb0 + (kv0));              \
    async_copy16(&VTsh[buf][(t + 256) * 8], vb0 + (size_t)32*2048 + (kv0)); \
  } while (0)

  const int nt = (qtile + 1) * 2;
  STAGE(0, 0);
  __syncthreads();

  for (int ti = 0; ti < nt; ++ti) {
    const int kv0 = ti * 64;
    const int cur = ti & 1;
    if (ti + 1 < nt) STAGE((ti + 1) * 64, cur ^ 1);

    if (kv0 <= q0 + 31) {
      const u16* Kc = Ksh[cur];
      const u16* Vc = VTsh[cur];

      f32x4 s[2][4] = {};
      __builtin_amdgcn_s_setprio(1);
#pragma unroll
      for (int f = 0; f < 4; ++f) {
        const int krow = f * 16 + lr;
        const int kswz = (krow & 7) << 4;
#pragma unroll
        for (int ks = 0; ks < 2; ++ks) {
          bf16x8 kb = *(const bf16x8*)&Kc[krow * 64 + (((ks * 64 + g * 16) ^ kswz) >> 1)];
          s[0][f] = MFMA16(qf[0][ks], kb, s[0][f]);
          s[1][f] = MFMA16(qf[1][ks], kb, s[1][f]);
        }
      }
      __builtin_amdgcn_s_setprio(0);

      const bool diag = (kv0 + 63 > q0);
#pragma unroll
      for (int mf = 0; mf < 2; ++mf)
#pragma unroll
        for (int f = 0; f < 4; ++f)
#pragma unroll
          for (int j = 0; j < 4; ++j) {
            float p = __expf(s[mf][f][j]);
            if (diag) {
              const int key = kv0 + f * 16 + lr;
              const int qrow = q0 + mf * 16 + g * 4 + j;
              p = (key <= qrow) ? p : 0.f;
            }
            s[mf][f][j] = p;
            lrun[mf][j] += p;
          }

#pragma unroll
      for (int mf = 0; mf < 2; ++mf)
#pragma unroll
        for (int f = 0; f < 4; ++f)
#pragma unroll
          for (int j = 0; j < 4; ++j) {
            const int prow = mf * 16 + g * 4 + j;
            Psh[w][prow * 64 + (((f * 32 + lr * 2) ^ ((prow & 7) << 4)) >> 1)] =
                f2bf(s[mf][f][j]);
          }

#pragma unroll
      for (int ks = 0; ks < 2; ++ks) {
        bf16x8 pa[2];
#pragma unroll
        for (int mf = 0; mf < 2; ++mf) {
          const int prow = mf * 16 + lr;
          pa[mf] = *(const bf16x8*)&Psh[w][prow * 64 + (((ks * 64 + g * 16) ^ ((prow & 7) << 4)) >> 1)];
        }
        __builtin_amdgcn_s_setprio(1);
#pragma unroll
        for (int nf = 0; nf < 4; ++nf) {
          const int vrow = nf * 16 + lr;
          bf16x8 vb = *(const bf16x8*)&Vc[vrow * 64 + (((ks * 64 + g * 16) ^ ((vrow & 7) << 4)) >> 1)];
          oacc[0][nf] = MFMA16(pa[0], vb, oacc[0][nf]);
          oacc[1][nf] = MFMA16(pa[1], vb, oacc[1][nf]);
        }
        __builtin_amdgcn_s_setprio(0);
      }
    }
    __syncthreads();
  }
#undef STAGE

  float linv[2][4];
#pragma unroll
  for (int mf = 0; mf < 2; ++mf)
#pragma unroll
    for (int j = 0; j < 4; ++j) {
      float s = lrun[mf][j];
#pragma unroll
      for (int d = 1; d < 16; d <<= 1) s += __shfl_xor(s, d, 64);
      linv[mf][j] = 1.f / s;
    }

  const int b = bh >> 4, h = bh & 15;
#pragma unroll
  for (int mf = 0; mf < 2; ++mf)
#pragma unroll
    for (int nf = 0; nf < 4; ++nf) {
      const int col = nf * 16 + lr;
#pragma unroll
      for (int j = 0; j < 4; ++j) {
        const int row = q0 + mf * 16 + g * 4 + j;
        const float o = oacc[mf][nf][j] * linv[mf][j];
        ybf[((size_t)b * 2048 + row) * 1024 + h * 64 + col] = f2bf(o);
      }
    }
}

// ---------- launch ----------
extern "C" void kernel_launch(void* const* d_in, const int* in_sizes, int n_in,
                              void* d_out, int out_size, void* d_ws, size_t ws_size,
                              hipStream_t stream) {
  const float* x     = (const float*)d_in[0];   // [4,2048,1024]
  const float* wqkv  = (const float*)d_in[1];   // [1024,3072]
  const float* wproj = (const float*)d_in[2];   // [1024,1024]
  float* out = (float*)d_out;                   // [4,2048,1024] f32

  char* ws = (char*)d_ws;
  u16* xbf    = (u16*)ws;
  u16* ybf    = xbf;  // alias (x dead after qkv GEMM)
  u16* wqkvT  = (u16*)(ws + 16777216);
  u16* wprojT = (u16*)(ws + 16777216 + 6291456);
  u16* qws    = (u16*)(ws + 25165824);
  u16* kws    = (u16*)(ws + 41943040);
  u16* vtws   = (u16*)(ws + 58720256);

  cvt_bf16_kernel<<<2048, 256, 0, stream>>>(x, xbf, (8192 * 1024) / 4);
  transpose_cvt_kernel<<<dim3(3072 / 32, 1024 / 32), 256, 0, stream>>>(wqkv, wqkvT, 1024, 3072);
  transpose_cvt_kernel<<<dim3(1024 / 32, 1024 / 32), 256, 0, stream>>>(wproj, wprojT, 1024, 1024);
  // qkv GEMM: M=8192 N=3072 K=1024, 256^2 8-phase (384 blocks)
  gemm8ph<<<dim3(32, 12), 512, 0, stream>>>(xbf, wqkvT, qws, kws, vtws);
  attn_kernel<<<16 * 64, 256, 0, stream>>>(qws, kws, vtws, ybf);
  // proj GEMM: M=8192 N=1024 K=1024 (512 blocks = 1.0 occupancy wave at 2/CU)
  gemm2ph<<<dim3(64, 8), 256, 0, stream>>>(ybf, wprojT, 1024, 1024, out);
}

// Round 8
// 176.422 us; speedup vs baseline: 1.1124x; 1.1124x over previous
//
#include <hip/hip_runtime.h>
#include <stdint.h>

typedef unsigned short u16;
typedef unsigned int u32;
typedef __attribute__((ext_vector_type(8))) short bf16x8;
typedef __attribute__((ext_vector_type(4))) float f32x4;
typedef __attribute__((ext_vector_type(16))) float f32x16;

// ---------- helpers ----------
__device__ __forceinline__ u16 f2bf(float f) {
  union { float f; unsigned u; } v; v.f = f;
  unsigned r = v.u + 0x7fffu + ((v.u >> 16) & 1u);  // round-to-nearest-even
  return (u16)(r >> 16);
}

__device__ __forceinline__ u32 pk_bf16(float lo, float hi) {
  u32 r;
  asm("v_cvt_pk_bf16_f32 %0, %1, %2" : "=v"(r) : "v"(lo), "v"(hi));
  return r;
}
#define PLSWAP(a, b) asm volatile("v_permlane32_swap_b32 %0, %1" : "+v"(a), "+v"(b))

__device__ __forceinline__ void async_copy16(u16* lds_dst, const u16* g_src) {
  __builtin_amdgcn_global_load_lds(
      (const __attribute__((address_space(1))) unsigned*)(g_src),
      (__attribute__((address_space(3))) unsigned*)(lds_dst),
      16, 0, 0);
}

#define MFMA16(a, b, c) __builtin_amdgcn_mfma_f32_16x16x32_bf16((a), (b), (c), 0, 0, 0)
#define MFMA32(a, b, c) __builtin_amdgcn_mfma_f32_32x32x16_bf16((a), (b), (c), 0, 0, 0)

// ---------- convert f32 -> bf16 (vectorized) ----------
__global__ void cvt_bf16_kernel(const float* __restrict__ in, u16* __restrict__ out, int n4) {
  int i = blockIdx.x * blockDim.x + threadIdx.x;
  int stride = gridDim.x * blockDim.x;
  for (; i < n4; i += stride) {
    float4 v = ((const float4*)in)[i];
    ushort4 o;
    o.x = f2bf(v.x); o.y = f2bf(v.y); o.z = f2bf(v.z); o.w = f2bf(v.w);
    ((ushort4*)out)[i] = o;
  }
}

// ---------- tiled transpose + convert: in [R][C] f32 -> out [C][R] bf16 ----------
__global__ void transpose_cvt_kernel(const float* __restrict__ in, u16* __restrict__ out,
                                     int R, int C) {
  __shared__ float tile[32][33];
  int bx = blockIdx.x * 32;
  int by = blockIdx.y * 32;
  int tx = threadIdx.x & 31, ty = threadIdx.x >> 5;
#pragma unroll
  for (int j = 0; j < 32; j += 8)
    tile[ty + j][tx] = in[(size_t)(by + ty + j) * C + bx + tx];
  __syncthreads();
#pragma unroll
  for (int j = 0; j < 32; j += 8)
    out[(size_t)(bx + ty + j) * R + by + tx] = f2bf(tile[tx][ty + j]);
}

// ---------- 2-phase 128x128 GEMM: C = A[M][K] * BT[N][K]^T ----------
// Proven round-6 structure: full LDS dbuf, STAGE(T+1) before compute(T),
// one barrier per K-tile. XOR-swizzle (row&7)<<4 via pre-swizzled source.
// MODE 0: qkv scatter epilogue (q*0.125, k, vT bf16); MODE 1: f32 [M][N].
template<int MODE>
__global__ __launch_bounds__(256, 2)
void gemm2ph(const u16* __restrict__ A, const u16* __restrict__ BT,
             int K, int N,
             u16* __restrict__ q_o, u16* __restrict__ k_o, u16* __restrict__ vt_o,
             float* __restrict__ f_o) {
  __shared__ u16 As[2][128 * 64];
  __shared__ u16 Bs[2][128 * 64];

  const int t = threadIdx.x;
  const int w = t >> 6, l = t & 63;
  const int lr = l & 15, g = l >> 4;
  const int wm = (w >> 1) * 64, wn = (w & 1) * 64;
  const int m0 = blockIdx.x * 128, n0 = blockIdx.y * 128;

  const int r = t >> 3;
  const int sw = ((t & 7) * 16) ^ ((r & 7) << 4);
  const u16* pA = A + (size_t)(m0 + r) * K + (sw >> 1);
  const u16* pB = BT + (size_t)(n0 + r) * K + (sw >> 1);

#define STG(buf, kk)                                                    \
  do {                                                                  \
    async_copy16(&As[buf][t * 8],        pA + (kk));                    \
    async_copy16(&As[buf][2048 + t * 8], pA + (size_t)32 * K + (kk));   \
    async_copy16(&As[buf][4096 + t * 8], pA + (size_t)64 * K + (kk));   \
    async_copy16(&As[buf][6144 + t * 8], pA + (size_t)96 * K + (kk));   \
    async_copy16(&Bs[buf][t * 8],        pB + (kk));                    \
    async_copy16(&Bs[buf][2048 + t * 8], pB + (size_t)32 * K + (kk));   \
    async_copy16(&Bs[buf][4096 + t * 8], pB + (size_t)64 * K + (kk));   \
    async_copy16(&Bs[buf][6144 + t * 8], pB + (size_t)96 * K + (kk));   \
  } while (0)

  f32x4 acc[4][4] = {};

  STG(0, 0);
  __syncthreads();

  const int NTt = K / 64;
  for (int T = 0; T < NTt; ++T) {
    const int cur = T & 1;
    if (T + 1 < NTt) STG(cur ^ 1, (T + 1) * 64);

    bf16x8 af[4][2], bfr[4][2];
#pragma unroll
    for (int mf = 0; mf < 4; ++mf)
#pragma unroll
      for (int ks = 0; ks < 2; ++ks) {
        const int row = wm + mf * 16 + lr;
        af[mf][ks] = *(const bf16x8*)&As[cur][row * 64 + (((ks * 64 + g * 16) ^ ((row & 7) << 4)) >> 1)];
      }
#pragma unroll
    for (int nf = 0; nf < 4; ++nf)
#pragma unroll
      for (int ks = 0; ks < 2; ++ks) {
        const int row = wn + nf * 16 + lr;
        bfr[nf][ks] = *(const bf16x8*)&Bs[cur][row * 64 + (((ks * 64 + g * 16) ^ ((row & 7) << 4)) >> 1)];
      }
#pragma unroll
    for (int mf = 0; mf < 4; ++mf)
#pragma unroll
      for (int nf = 0; nf < 4; ++nf) {
        acc[mf][nf] = MFMA16(af[mf][0], bfr[nf][0], acc[mf][nf]);
        acc[mf][nf] = MFMA16(af[mf][1], bfr[nf][1], acc[mf][nf]);
      }
    __syncthreads();
  }
#undef STG

#pragma unroll
  for (int mf = 0; mf < 4; ++mf) {
#pragma unroll
    for (int nf = 0; nf < 4; ++nf) {
      const int col = n0 + wn + nf * 16 + lr;
#pragma unroll
      for (int j = 0; j < 4; ++j) {
        const int row = m0 + wm + mf * 16 + g * 4 + j;
        const float v = acc[mf][nf][j];
        if (MODE == 0) {
          const int which = col >> 10, rr = col & 1023;
          const int h = rr >> 6, hd = rr & 63;
          const int b = row >> 11, s = row & 2047;
          const size_t bh = (size_t)b * 16 + h;
          if (which == 0)      q_o[(bh * 2048 + s) * 64 + hd] = f2bf(v * 0.125f);
          else if (which == 1) k_o[(bh * 2048 + s) * 64 + hd] = f2bf(v);
          else                 vt_o[(bh * 64 + hd) * 2048 + s] = f2bf(v);
        } else {
          f_o[(size_t)row * N + col] = v;
        }
      }
    }
  }
}

// ---------- flash attention (v4): swapped-QK^T 32x32, in-register softmax ----------
// grid: 16 qtiles (heavy-first) x 64 bh; 256 thr = 4 waves; wave = 32 q-rows
// (one per lane pair: q = q0w + (lane&31)). KVBLK=64, LDS double-buffered
// K[64][64] + VT[64][64], XOR-swizzled. No P LDS buffer:
//   S^T = mfma32(K_afrag, Q_bfrag)  -> lane owns q-row; exp/mask/lsum per-lane
//   P -> PV B-frag via v_cvt_pk_bf16_f32 + v_permlane32_swap_b32 (T12)
//   O^T = mfma32(VT_afrag, P_bfrag); l-reduce = one shfl_xor(32) at end.
__global__ __launch_bounds__(256, 2)
void attn_kernel(const u16* __restrict__ qws, const u16* __restrict__ kws,
                 const u16* __restrict__ vtws, u16* __restrict__ ybf) {
  __shared__ u16 Ksh[2][64 * 64];   // [key][hd], swizzled
  __shared__ u16 VTsh[2][64 * 64];  // [hd][key], swizzled

  const int bh = blockIdx.x & 63;
  const int qtile = 15 - (blockIdx.x >> 6);  // heavy blocks first
  const int t = threadIdx.x;
  const int w = t >> 6, l = t & 63;
  const int lq = l & 31;   // lane's q within wave
  const int h = l >> 5;    // half (k-group) index
  const int q0 = qtile * 128 + w * 32;
  const int qg = q0 + lq;  // global q row

  // Q B-frags (Q pre-scaled 0.125): qf[s] = Q[qg][s*16 + h*8 .. +7]
  bf16x8 qf[4];
  {
    const u16* qb = qws + ((size_t)bh * 2048 + qg) * 64 + h * 8;
#pragma unroll
    for (int s = 0; s < 4; ++s) qf[s] = *(const bf16x8*)(qb + s * 16);
  }

  f32x16 oacc[2] = {};  // O^T d-tiles (rows d, col q=lane&31)
  float lsum = 0.f;

  // staging (identical to v3): thread t covers rows (t>>3), (t>>3)+32 at
  // byte-seg (t&7)*16; source pre-swizzled so linear LDS dst lands swizzled
  const int srow = t >> 3;
  const int ssw = ((t & 7) * 16) ^ ((srow & 7) << 4);
  const u16* kb0 = kws + ((size_t)bh * 2048 + srow) * 64 + (ssw >> 1);
  const u16* vb0 = vtws + ((size_t)bh * 64 + srow) * 2048 + (ssw >> 1);

#define STAGE(kv0, buf)                                                \
  do {                                                                 \
    async_copy16(&Ksh[buf][t * 8],          kb0 + (size_t)(kv0)*64);   \
    async_copy16(&Ksh[buf][(t + 256) * 8],  kb0 + (size_t)((kv0)+32)*64); \
    async_copy16(&VTsh[buf][t * 8],         vb0 + (kv0));              \
    async_copy16(&VTsh[buf][(t + 256) * 8], vb0 + (size_t)32*2048 + (kv0)); \
  } while (0)

  const int nt = (qtile + 1) * 2;
  STAGE(0, 0);
  __syncthreads();

  for (int ti = 0; ti < nt; ++ti) {
    const int kv0 = ti * 64;
    const int cur = ti & 1;
    if (ti + 1 < nt) STAGE((ti + 1) * 64, cur ^ 1);

    if (kv0 <= q0 + 31) {
      const u16* Kc = Ksh[cur];
      const u16* Vc = VTsh[cur];

      // ---- S^T[kt] = mfma32(K, Q): rows=keys(kt*32+..), col=q=lane&31 ----
      f32x16 st[2] = {};
      __builtin_amdgcn_s_setprio(1);
#pragma unroll
      for (int kt = 0; kt < 2; ++kt) {
        const int row = kt * 32 + lq;
        const int swz = (row & 7) << 4;
#pragma unroll
        for (int s = 0; s < 4; ++s) {
          bf16x8 kf = *(const bf16x8*)&Kc[row * 64 + (((s * 32 + h * 16) ^ swz) >> 1)];
          st[kt] = MFMA32(kf, qf[s], st[kt]);
        }
      }
      __builtin_amdgcn_s_setprio(0);

      // ---- softmax-lite: p = exp(s), mask on diagonal tiles, per-lane lsum ----
      const bool diag = (kv0 + 63 > q0);
#pragma unroll
      for (int kt = 0; kt < 2; ++kt)
#pragma unroll
        for (int p = 0; p < 16; ++p) {
          float e = __expf(st[kt][p]);
          if (diag) {
            const int key = kv0 + kt * 32 + (p & 3) + 8 * (p >> 2) + 4 * h;
            e = (key <= qg) ? e : 0.f;
          }
          st[kt][p] = e;
          lsum += e;
        }

      // ---- P -> B-frags in-register: cvt_pk + permlane32_swap ----
      // per 16-key slice s2 = kt*2+s2l: words [L0,L1,H0,H1] post-swap give
      // lane (q, h) its 8 consecutive keys 16*s2 + 8h + 0..7
      bf16x8 pb[4];
#pragma unroll
      for (int kt = 0; kt < 2; ++kt)
#pragma unroll
        for (int s2l = 0; s2l < 2; ++s2l) {
          const int p0 = s2l * 8;
          u32 L0 = pk_bf16(st[kt][p0 + 0], st[kt][p0 + 1]);
          u32 L1 = pk_bf16(st[kt][p0 + 2], st[kt][p0 + 3]);
          u32 H0 = pk_bf16(st[kt][p0 + 4], st[kt][p0 + 5]);
          u32 H1 = pk_bf16(st[kt][p0 + 6], st[kt][p0 + 7]);
          PLSWAP(L0, H0);  // L0 -> word0, H0 -> word2
          PLSWAP(L1, H1);  // L1 -> word1, H1 -> word3
          union { u32 u[4]; bf16x8 v; } pw;
          pw.u[0] = L0; pw.u[1] = L1; pw.u[2] = H0; pw.u[3] = H1;
          pb[kt * 2 + s2l] = pw.v;
        }

      // ---- O^T[dt] += mfma32(VT, P) over 4 key-slices ----
      __builtin_amdgcn_s_setprio(1);
#pragma unroll
      for (int dt = 0; dt < 2; ++dt) {
        const int row = dt * 32 + lq;
        const int swz = (row & 7) << 4;
#pragma unroll
        for (int s2 = 0; s2 < 4; ++s2) {
          bf16x8 vf = *(const bf16x8*)&Vc[row * 64 + (((s2 * 32 + h * 16) ^ swz) >> 1)];
          oacc[dt] = MFMA32(vf, pb[s2], oacc[dt]);
        }
      }
      __builtin_amdgcn_s_setprio(0);
    }
    __syncthreads();
  }
#undef STAGE

  // ---- epilogue: l-reduce across halves, scale, pack, b64 stores ----
  lsum += __shfl_xor(lsum, 32, 64);
  const float linv = 1.f / lsum;

  const int b = bh >> 4, hh = bh & 15;
  u16* yb = ybf + ((size_t)b * 2048 + qg) * 1024 + hh * 64;
#pragma unroll
  for (int dt = 0; dt < 2; ++dt)
#pragma unroll
    for (int pg = 0; pg < 4; ++pg) {
      // regs pg*4..+3 = d = dt*32 + 8*pg + 4*h + 0..3 (consecutive)
      u32 w0 = pk_bf16(oacc[dt][pg * 4 + 0] * linv, oacc[dt][pg * 4 + 1] * linv);
      u32 w1 = pk_bf16(oacc[dt][pg * 4 + 2] * linv, oacc[dt][pg * 4 + 3] * linv);
      union { u32 u[2]; unsigned long long ll; } pk2;
      pk2.u[0] = w0; pk2.u[1] = w1;
      *(unsigned long long*)(yb + dt * 32 + 8 * pg + 4 * h) = pk2.ll;
    }
}

// ---------- launch ----------
extern "C" void kernel_launch(void* const* d_in, const int* in_sizes, int n_in,
                              void* d_out, int out_size, void* d_ws, size_t ws_size,
                              hipStream_t stream) {
  const float* x     = (const float*)d_in[0];   // [4,2048,1024]
  const float* wqkv  = (const float*)d_in[1];   // [1024,3072]
  const float* wproj = (const float*)d_in[2];   // [1024,1024]
  float* out = (float*)d_out;                   // [4,2048,1024] f32

  char* ws = (char*)d_ws;
  u16* xbf    = (u16*)ws;
  u16* ybf    = xbf;  // alias (x dead after qkv GEMM)
  u16* wqkvT  = (u16*)(ws + 16777216);
  u16* wprojT = (u16*)(ws + 16777216 + 6291456);
  u16* qws    = (u16*)(ws + 25165824);
  u16* kws    = (u16*)(ws + 41943040);
  u16* vtws   = (u16*)(ws + 58720256);

  cvt_bf16_kernel<<<2048, 256, 0, stream>>>(x, xbf, (8192 * 1024) / 4);
  transpose_cvt_kernel<<<dim3(3072 / 32, 1024 / 32), 256, 0, stream>>>(wqkv, wqkvT, 1024, 3072);
  transpose_cvt_kernel<<<dim3(1024 / 32, 1024 / 32), 256, 0, stream>>>(wproj, wprojT, 1024, 1024);
  gemm2ph<0><<<dim3(64, 24), 256, 0, stream>>>(xbf, wqkvT, 1024, 3072, qws, kws, vtws, nullptr);
  attn_kernel<<<16 * 64, 256, 0, stream>>>(qws, kws, vtws, ybf);
  gemm2ph<1><<<dim3(64, 8), 256, 0, stream>>>(ybf, wprojT, 1024, 1024, nullptr, nullptr, nullptr, out);
}